// Round 3
// baseline (588.345 us; speedup 1.0000x reference)
//
#include <hip/hip_runtime.h>
#include <hip/hip_bf16.h>
#include <stdint.h>

#define NVOX 131072
#define CCH  128
#define EPSV 1e-4f

typedef __bf16 bf16_t;
typedef bf16_t bf16x8 __attribute__((ext_vector_type(8)));
typedef bf16_t bf16x4 __attribute__((ext_vector_type(4)));
typedef float  f32x4  __attribute__((ext_vector_type(4)));

__device__ __forceinline__ void async16(void* lds, const void* g) {
    __builtin_amdgcn_global_load_lds(
        (const __attribute__((address_space(1))) uint32_t*)g,
        (__attribute__((address_space(3))) uint32_t*)lds, 16, 0, 0);
}

// ---------- prep: features f32 -> bf16 ----------
__global__ void k_prep_feat(const float* __restrict__ f, bf16_t* __restrict__ fb) {
    int i = blockIdx.x * 256 + threadIdx.x;      // over N*C/4 = 4194304 exactly
    const float4* f4 = (const float4*)f;
    float4 v = f4[i];
    bf16x4 o;
    o[0] = (bf16_t)v.x; o[1] = (bf16_t)v.y; o[2] = (bf16_t)v.z; o[3] = (bf16_t)v.w;
    ((bf16x4*)fb)[i] = o;
}

// ---------- prep: zero rows + stats ----------
__global__ void k_prep_misc(bf16_t* featb, bf16_t* xb1, bf16_t* xb2, float* stats) {
    int t = threadIdx.x;
    if (t < 128) {
        featb[(size_t)NVOX * CCH + t] = (bf16_t)0.0f;
        xb1[(size_t)NVOX * CCH + t]   = (bf16_t)0.0f;
        xb2[(size_t)NVOX * CCH + t]   = (bf16_t)0.0f;
    }
    for (int i = t; i < 768; i += 256) stats[i] = 0.0f;
}

// ---------- prep: W [27,Ci,Co] f32 -> W^T [k][co][ci] bf16, 3 layers ----------
__global__ void k_prep_w(const float* __restrict__ w0, const float* __restrict__ w1,
                         const float* __restrict__ w2, bf16_t* __restrict__ wbt) {
    int blk = blockIdx.x;                // 0..80
    int layer = blk / 27, k = blk % 27;
    const float* w = (layer == 0 ? w0 : (layer == 1 ? w1 : w2)) + k * 16384;
    __shared__ bf16_t tile[128][132];
    for (int e = threadIdx.x; e < 16384; e += 256) {
        int ci = e >> 7, co = e & 127;
        tile[co][ci] = (bf16_t)w[e];
    }
    __syncthreads();
    bf16_t* out = wbt + (size_t)blk * 16384;
    for (int e = threadIdx.x; e < 16384; e += 256) {
        int co = e >> 7, ci = e & 127;
        out[e] = tile[co][ci];
    }
}

// ---------- conv: gather-GEMM, BM=256, 8 waves, pipelined, 64KB static LDS ----
// Per phase t (K-chunk 32): ds_read A/B frags | issue B(t+1), A(t+2) |
// barrier | lgkmcnt(0) | setprio(1) 16xMFMA setprio(0) | vmcnt(2) | barrier.
// vmcnt(2) keeps exactly A(t+2)'s two loads in flight across the barrier
// (counted vmcnt, never 0 in steady state). Gather indices live in registers,
// prefetched 2 k-groups ahead from nbr (no offs table in LDS).
// LDS 65536 = A 3x16384 (256 rows x 64B) + B 2x8192 (128 rows x 64B);
// epilogue stats reuse smA.
__global__ __launch_bounds__(512, 2) void k_conv(
        const bf16_t* __restrict__ featb,   // (N+1) x 128 bf16
        const bf16_t* __restrict__ wbt,     // 27 x 128co x 128ci bf16
        const int* __restrict__ nbr,        // N x 27 int32
        float* __restrict__ out,            // N x 128 f32
        float* __restrict__ stat)           // [0..127]=sum, [128..255]=sumsq
{
    __shared__ __align__(16) char smem[65536];
    char* smA = smem;              // 3 x 16384
    char* smB = smem + 49152;      // 2 x 8192

    const int tid = threadIdx.x;
    const int m0 = blockIdx.x << 8;          // 256 rows per block

    const int l = tid & 63, w = tid >> 6;    // 8 waves
    const int wm = w >> 1, wn = w & 1;       // 4M x 2N wave grid, 64x64 per wave
    const int lrow = l & 15, lq = l >> 4;

    const int rA = tid >> 2;                 // staging row 0..127
    const int swz  = (((tid & 3) ^ ((rA >> 1) & 3)) << 4);   // source-side swizzle
    const int cxor = ((lq ^ ((lrow >> 1) & 3)) << 4);        // read-side swizzle

    const char* fbase = (const char*)featb;
    const char* wbase = (const char*)wbt;
    const int* nb0 = nbr + (size_t)(m0 + rA) * 27;
    const int* nb1 = nbr + (size_t)(m0 + rA + 128) * 27;

    f32x4 acc[4][4] = {};

    auto B_ISSUE = [&](int bw, int kb, int cb) {
        const char* wk = wbase + ((size_t)kb << 15);          // k * 128*128*2
        char* dB = smB + (bw << 13) + (w << 10);
        async16(dB, wk + (rA << 8) + (cb << 6) + swz);
    };
    auto A_ISSUE = [&](int aw, int ca, int ia0, int ia1) {
        uint32_t o0 = ((uint32_t)(ia0 < 0 ? NVOX : ia0)) << 8;
        uint32_t o1 = ((uint32_t)(ia1 < 0 ? NVOX : ia1)) << 8;
        const int cb = ca << 6;
        char* dA = smA + (aw << 14) + (w << 10);
        async16(dA,        fbase + o0 + cb + swz);
        async16(dA + 8192, fbase + o1 + cb + swz);
    };

    // wsel: 0 -> vmcnt(2)+bar, 1 -> vmcnt(0)+bar, 2 -> none
    auto PHASE = [&](int a_rd, int b_rd,
                     bool doB, int bw, int kb, int cb,
                     bool doA, int aw, int ca, int ia0, int ia1,
                     int wsel) {
        const char* bA = smA + (a_rd << 14);
        const char* bB = smB + (b_rd << 13);
        bf16x8 af[4], bfr[4];
        #pragma unroll
        for (int i = 0; i < 4; ++i) {
            af[i]  = *(const bf16x8*)(bA + (((wm << 6) + (i << 4) + lrow) << 6) + cxor);
            bfr[i] = *(const bf16x8*)(bB + (((wn << 6) + (i << 4) + lrow) << 6) + cxor);
        }
        if (doB) B_ISSUE(bw, kb, cb);
        if (doA) A_ISSUE(aw, ca, ia0, ia1);
        __builtin_amdgcn_sched_barrier(0);
        __builtin_amdgcn_s_barrier();                         // entry barrier
        asm volatile("s_waitcnt lgkmcnt(0)" ::: "memory");
        __builtin_amdgcn_sched_barrier(0);
        __builtin_amdgcn_s_setprio(1);
        #pragma unroll
        for (int i = 0; i < 4; ++i)
            #pragma unroll
            for (int j = 0; j < 4; ++j)
                acc[i][j] = __builtin_amdgcn_mfma_f32_16x16x32_bf16(
                    af[i], bfr[j], acc[i][j], 0, 0, 0);
        __builtin_amdgcn_s_setprio(0);
        if (wsel == 0) {
            asm volatile("s_waitcnt vmcnt(2)" ::: "memory");  // keep A(t+2) in flight
            __builtin_amdgcn_sched_barrier(0);
            __builtin_amdgcn_s_barrier();
        } else if (wsel == 1) {
            asm volatile("s_waitcnt vmcnt(0)" ::: "memory");
            __builtin_amdgcn_sched_barrier(0);
            __builtin_amdgcn_s_barrier();
        }
    };

    // prologue: gather indices for k-groups 0,1; stage B(0), A(0), A(1)
    int iA0 = nb0[0], iA1 = nb1[0];
    int iB0 = nb0[1], iB1 = nb1[1];
    __builtin_amdgcn_sched_barrier(0);
    B_ISSUE(0, 0, 0);
    A_ISSUE(0, 0, iA0, iA1);
    A_ISSUE(1, 1, iA0, iA1);
    asm volatile("s_waitcnt vmcnt(2)" ::: "memory");          // B(0),A(0) landed
    __builtin_amdgcn_sched_barrier(0);
    __builtin_amdgcn_s_barrier();

    // main loop: 27 k-taps x 4 chunks = 108 phases; t = 4u+c
    #pragma unroll 1
    for (int u = 0; u < 26; ++u) {
        const int ab  = u % 3;
        const int ab1 = (ab == 2) ? 0 : ab + 1;
        const int ab2 = (ab1 == 2) ? 0 : ab1 + 1;
        const int kc = (u + 2 < 27) ? u + 2 : 26;
        int iC0 = nb0[kc], iC1 = nb1[kc];                     // prefetch group u+2
        __builtin_amdgcn_sched_barrier(0);                    // pin nbr before issues
        PHASE(ab,  0, true, 1, u,     1, true, ab2, 2, iA0, iA1, 0);  // t=4u
        PHASE(ab1, 1, true, 0, u,     2, true, ab,  3, iA0, iA1, 0);  // t=4u+1
        PHASE(ab2, 0, true, 1, u,     3, true, ab1, 0, iB0, iB1, 0);  // t=4u+2
        PHASE(ab,  1, true, 0, u + 1, 0, true, ab2, 1, iB0, iB1, 0);  // t=4u+3
        iA0 = iB0; iA1 = iB1; iB0 = iC0; iB1 = iC1;
    }
    // tail: u=26 (ab=2), phases 104..107
    PHASE(2, 0, true,  1, 26, 1, true,  1, 2, iA0, iA1, 0);   // t=104
    PHASE(0, 1, true,  0, 26, 2, true,  2, 3, iA0, iA1, 0);   // t=105
    PHASE(1, 0, true,  1, 26, 3, false, 0, 0, 0, 0, 1);       // t=106: vmcnt(0)
    PHASE(2, 1, false, 0, 0,  0, false, 0, 0, 0, 0, 2);       // t=107: no exit

    // epilogue: store + per-channel stats (stats buffers reuse smA)
    __syncthreads();
    float* ssum = (float*)smA;
    float* ssq  = ssum + 128;
    if (tid < 128) { ssum[tid] = 0.0f; ssq[tid] = 0.0f; }
    __syncthreads();

    float csum[4] = {0, 0, 0, 0}, csq[4] = {0, 0, 0, 0};
    #pragma unroll
    for (int j = 0; j < 4; ++j) {
        int col = (wn << 6) + (j << 4) + lrow;
        #pragma unroll
        for (int i = 0; i < 4; ++i) {
            int grow = m0 + (wm << 6) + (i << 4) + (lq << 2);
            #pragma unroll
            for (int r = 0; r < 4; ++r) {
                float v = acc[i][j][r];
                out[(size_t)(grow + r) * CCH + col] = v;
                csum[j] += v;
                csq[j]  += v * v;
            }
        }
    }
    #pragma unroll
    for (int j = 0; j < 4; ++j) {
        csum[j] += __shfl_xor(csum[j], 16, 64);
        csum[j] += __shfl_xor(csum[j], 32, 64);
        csq[j]  += __shfl_xor(csq[j], 16, 64);
        csq[j]  += __shfl_xor(csq[j], 32, 64);
    }
    if (lq == 0) {
        #pragma unroll
        for (int j = 0; j < 4; ++j) {
            int col = (wn << 6) + (j << 4) + lrow;
            atomicAdd(&ssum[col], csum[j]);
            atomicAdd(&ssq[col],  csq[j]);
        }
    }
    __syncthreads();
    if (tid < 128) {
        atomicAdd(&stat[tid],       ssum[tid]);
        atomicAdd(&stat[128 + tid], ssq[tid]);
    }
}

// ---------- BN + LeakyReLU -> bf16 next-layer input ----------
__global__ void k_bnact(const float* __restrict__ x, const float* __restrict__ stat,
                        const float* __restrict__ g, const float* __restrict__ b,
                        bf16_t* __restrict__ out, float slope) {
    __shared__ float sc[128], sh[128];
    int tid = threadIdx.x;
    if (tid < 128) {
        float mu  = stat[tid] * (1.0f / NVOX);
        float var = stat[128 + tid] * (1.0f / NVOX) - mu * mu;
        float inv = rsqrtf(var + EPSV);
        float s = g[tid] * inv;
        sc[tid] = s;
        sh[tid] = b[tid] - mu * s;
    }
    __syncthreads();
    int i = blockIdx.x * 256 + tid;              // over N*C/4
    float4 v = ((const float4*)x)[i];
    int c = (i << 2) & 127;
    float y0 = v.x * sc[c]     + sh[c];
    float y1 = v.y * sc[c + 1] + sh[c + 1];
    float y2 = v.z * sc[c + 2] + sh[c + 2];
    float y3 = v.w * sc[c + 3] + sh[c + 3];
    y0 = y0 >= 0.0f ? y0 : slope * y0;
    y1 = y1 >= 0.0f ? y1 : slope * y1;
    y2 = y2 >= 0.0f ? y2 : slope * y2;
    y3 = y3 >= 0.0f ? y3 : slope * y3;
    bf16x4 o;
    o[0] = (bf16_t)y0; o[1] = (bf16_t)y1; o[2] = (bf16_t)y2; o[3] = (bf16_t)y3;
    ((bf16x4*)out)[i] = o;
}

// ---------- BN3 + residual + LeakyReLU(1/3) -> f32 d_out ----------
__global__ void k_final(const float* __restrict__ x, const float* __restrict__ stat,
                        const float* __restrict__ g, const float* __restrict__ b,
                        const bf16_t* __restrict__ res, float* __restrict__ out) {
    __shared__ float sc[128], sh[128];
    int tid = threadIdx.x;
    if (tid < 128) {
        float mu  = stat[tid] * (1.0f / NVOX);
        float var = stat[128 + tid] * (1.0f / NVOX) - mu * mu;
        float inv = rsqrtf(var + EPSV);
        float s = g[tid] * inv;
        sc[tid] = s;
        sh[tid] = b[tid] - mu * s;
    }
    __syncthreads();
    int i = blockIdx.x * 256 + tid;
    float4 v = ((const float4*)x)[i];
    bf16x4 r = ((const bf16x4*)res)[i];
    int c = (i << 2) & 127;
    float y0 = v.x * sc[c]     + sh[c]     + (float)r[0];
    float y1 = v.y * sc[c + 1] + sh[c + 1] + (float)r[1];
    float y2 = v.z * sc[c + 2] + sh[c + 2] + (float)r[2];
    float y3 = v.w * sc[c + 3] + sh[c + 3] + (float)r[3];
    const float k3 = 1.0f / 3.0f;
    y0 = y0 >= 0.0f ? y0 : k3 * y0;
    y1 = y1 >= 0.0f ? y1 : k3 * y1;
    y2 = y2 >= 0.0f ? y2 : k3 * y2;
    y3 = y3 >= 0.0f ? y3 : k3 * y3;
    float4 o; o.x = y0; o.y = y1; o.z = y2; o.w = y3;
    ((float4*)out)[i] = o;
}

extern "C" void kernel_launch(void* const* d_in, const int* in_sizes, int n_in,
                              void* d_out, int out_size, void* d_ws, size_t ws_size,
                              hipStream_t stream) {
    (void)in_sizes; (void)n_in; (void)out_size; (void)ws_size;
    const float* features = (const float*)d_in[0];
    const int*   nbr      = (const int*)d_in[1];
    const float* w1 = (const float*)d_in[2];
    const float* w2 = (const float*)d_in[3];
    const float* w3 = (const float*)d_in[4];
    const float* g1 = (const float*)d_in[5];
    const float* b1 = (const float*)d_in[6];
    const float* g2 = (const float*)d_in[7];
    const float* b2 = (const float*)d_in[8];
    const float* g3 = (const float*)d_in[9];
    const float* b3 = (const float*)d_in[10];

    char* ws = (char*)d_ws;
    const size_t SZ_FB = (size_t)(NVOX + 1) * CCH * 2;   // bf16 buffer w/ zero row
    bf16_t* featb    = (bf16_t*)(ws);
    bf16_t* xb1      = (bf16_t*)(ws + SZ_FB);
    bf16_t* xb2      = (bf16_t*)(ws + 2 * SZ_FB);
    float*  conv_out = (float*)(ws + 3 * SZ_FB);
    bf16_t* wbt      = (bf16_t*)(ws + 3 * SZ_FB + (size_t)NVOX * CCH * 4);
    float*  stats    = (float*)(ws + 3 * SZ_FB + (size_t)NVOX * CCH * 4
                                + (size_t)3 * 27 * 128 * 128 * 2);

    k_prep_feat<<<16384, 256, 0, stream>>>(features, featb);
    k_prep_misc<<<1, 256, 0, stream>>>(featb, xb1, xb2, stats);
    k_prep_w<<<81, 256, 0, stream>>>(w1, w2, w3, wbt);

    k_conv<<<512, 512, 0, stream>>>(featb, wbt, nbr, conv_out, stats);
    k_bnact<<<16384, 256, 0, stream>>>(conv_out, stats, g1, b1, xb1, 0.05f);

    k_conv<<<512, 512, 0, stream>>>(xb1, wbt + (size_t)27 * 16384, nbr, conv_out, stats + 256);
    k_bnact<<<16384, 256, 0, stream>>>(conv_out, stats + 256, g2, b2, xb2, 0.05f);

    k_conv<<<512, 512, 0, stream>>>(xb2, wbt + (size_t)2 * 27 * 16384, nbr, conv_out, stats + 512);
    k_final<<<16384, 256, 0, stream>>>(conv_out, stats + 512, g3, b3, xb1, (float*)d_out);
}